// Round 2
// baseline (150.067 us; speedup 1.0000x reference)
//
#include <hip/hip_runtime.h>
#include <hip/hip_bf16.h>
#include <math.h>

// Problem constants (K=4, R=16384, kappa=32, NX=3, NF=13, DOUT=64, n=16)
#define KR    65536   // K*R points
#define KAPPA 32

static __device__ __forceinline__ float bf2f(unsigned short u) {
  union { unsigned int i; float f; } v;
  v.i = ((unsigned int)u) << 16;
  return v.f;
}

// ---------------------------------------------------------------------------
// Kernel 1: Q[point][d] = dot(P[point], H[d]), P = [X|F] (16), stored bf16.
// 1024 blocks x 256 threads; each block handles 64 points.
// X/F staged to LDS with coalesced loads; compute reads are LDS broadcasts.
// ---------------------------------------------------------------------------
__global__ __launch_bounds__(256) void q_kernel(
    const float* __restrict__ X, const float* __restrict__ F,
    const float* __restrict__ H, __hip_bfloat16* __restrict__ Q) {
  __shared__ float Pl[64 * 16];   // P rows for 64 points
  const int t = threadIdx.x;
  const int base = blockIdx.x * 64;

  // stage X: 64*3 = 192 floats, coalesced
  if (t < 192) {
    const int p = t / 3, c = t % 3;
    Pl[p * 16 + c] = X[(size_t)base * 3 + t];
  }
  // stage F: 64*13 = 832 floats, coalesced
  for (int j = t; j < 832; j += 256) {
    const int p = j / 13, c = j % 13;
    Pl[p * 16 + 3 + c] = F[(size_t)base * 13 + j];
  }

  const int lane = t & 63;
  const int wave = t >> 6;
  // H is [64][16] row-major; lane d holds its row in 16 VGPRs
  const float4 h0 = *(const float4*)(H + lane * 16 + 0);
  const float4 h1 = *(const float4*)(H + lane * 16 + 4);
  const float4 h2 = *(const float4*)(H + lane * 16 + 8);
  const float4 h3 = *(const float4*)(H + lane * 16 + 12);
  __syncthreads();

  #pragma unroll 4
  for (int p = 0; p < 16; ++p) {
    const int lp = wave * 16 + p;
    const float* pp = Pl + lp * 16;   // wave-uniform -> LDS broadcast reads
    float q = pp[0] * h0.x + pp[1] * h0.y + pp[2] * h0.z + pp[3] * h0.w
            + pp[4] * h1.x + pp[5] * h1.y + pp[6] * h1.z + pp[7] * h1.w
            + pp[8] * h2.x + pp[9] * h2.y + pp[10] * h2.z + pp[11] * h2.w
            + pp[12] * h3.x + pp[13] * h3.y + pp[14] * h3.z + pp[15] * h3.w;
    Q[(size_t)(base + lp) * 64 + lane] = __float2bfloat16(q);
  }
}

// ---------------------------------------------------------------------------
// Kernel 2: m[d] = max(0, max_i Q[k, N[k,r,i], d]);  Y = relu(m @ gamma + b)
// 1024 blocks x 256 threads, 64 points/block.
// XCD swizzle: XCD(b) = b%8 (round-robin heuristic); XCD pair {2k,2k+1}
// serves only k-slice k, so each XCD's gather working set is one bf16
// Q-slice (2 MiB) -> L2-resident.
// ---------------------------------------------------------------------------
__global__ __launch_bounds__(256) void gather_gemm_kernel(
    const unsigned short* __restrict__ Q, const int* __restrict__ N,
    const float* __restrict__ gamma, const float* __restrict__ gbias,
    float* __restrict__ Y) {
  __shared__ float Gl[64 * 64];   // gamma[d][e], 16 KB
  __shared__ float Ml[64 * 68];   // M[p][d], padded stride, 17 KB
  __shared__ float Bl[64];

  const int t = threadIdx.x;
  // stage gamma as float4: 1024 float4 / 256 threads = 4 each
  {
    const float4* gsrc = (const float4*)gamma;
    float4* gdst = (float4*)Gl;
    #pragma unroll
    for (int i = 0; i < 4; ++i) gdst[t + 256 * i] = gsrc[t + 256 * i];
    if (t < 64) Bl[t] = gbias[t];
  }

  // XCD-aware bijective remap of blockIdx -> point block (1024 = 8 xcd x 128)
  const int b = blockIdx.x;
  const int xcd = b & 7;
  const int idx = b >> 3;          // 0..127
  const int k = xcd >> 1;          // 0..3
  const int half = xcd & 1;        // 0..1
  const int base = (k * 256 + half * 128 + idx) * 64;  // first point

  const int lane = t & 63;
  const int wave = t >> 6;
  const unsigned short* Qk = Q + ((size_t)k << 20);   // k * R * 64

  // ---- Phase A: max-gather 16 points per wave ----
  for (int p = 0; p < 16; ++p) {
    const int point = base + wave * 16 + p;
    const int4* np4 = (const int4*)(N + (size_t)point * KAPPA);
    float m = 0.0f;   // fold relu: relu(max_i q) == max(0, max_i q)
    #pragma unroll
    for (int j = 0; j < 8; ++j) {
      const int4 c = np4[j];      // wave-uniform 16B load
      m = fmaxf(m, bf2f(Qk[(size_t)c.x * 64 + lane]));
      m = fmaxf(m, bf2f(Qk[(size_t)c.y * 64 + lane]));
      m = fmaxf(m, bf2f(Qk[(size_t)c.z * 64 + lane]));
      m = fmaxf(m, bf2f(Qk[(size_t)c.w * 64 + lane]));
    }
    Ml[(wave * 16 + p) * 68 + lane] = m;
  }
  __syncthreads();

  // ---- Phase B: out(64x64) = Ml(64x64) @ Gl(64x64), 4x4 per thread ----
  const int ty = t >> 4;   // 0..15 -> point rows ty*4..ty*4+3
  const int tx = t & 15;   // 0..15 -> out cols  tx*4..tx*4+3
  float acc[4][4] = {};
  #pragma unroll 4
  for (int d = 0; d < 64; ++d) {
    const float a0 = Ml[(ty * 4 + 0) * 68 + d];
    const float a1 = Ml[(ty * 4 + 1) * 68 + d];
    const float a2 = Ml[(ty * 4 + 2) * 68 + d];
    const float a3 = Ml[(ty * 4 + 3) * 68 + d];
    const float4 bv = *(const float4*)(Gl + d * 64 + tx * 4);
    acc[0][0] += a0 * bv.x; acc[0][1] += a0 * bv.y; acc[0][2] += a0 * bv.z; acc[0][3] += a0 * bv.w;
    acc[1][0] += a1 * bv.x; acc[1][1] += a1 * bv.y; acc[1][2] += a1 * bv.z; acc[1][3] += a1 * bv.w;
    acc[2][0] += a2 * bv.x; acc[2][1] += a2 * bv.y; acc[2][2] += a2 * bv.z; acc[2][3] += a2 * bv.w;
    acc[3][0] += a3 * bv.x; acc[3][1] += a3 * bv.y; acc[3][2] += a3 * bv.z; acc[3][3] += a3 * bv.w;
  }

  // epilogue: add bias, relu, coalesced float4 stores
  const float4 bb = *(const float4*)(Bl + tx * 4);
  #pragma unroll
  for (int i = 0; i < 4; ++i) {
    float4 o;
    o.x = fmaxf(acc[i][0] + bb.x, 0.0f);
    o.y = fmaxf(acc[i][1] + bb.y, 0.0f);
    o.z = fmaxf(acc[i][2] + bb.z, 0.0f);
    o.w = fmaxf(acc[i][3] + bb.w, 0.0f);
    *(float4*)(Y + (size_t)(base + ty * 4 + i) * 64 + tx * 4) = o;
  }
}

extern "C" void kernel_launch(void* const* d_in, const int* in_sizes, int n_in,
                              void* d_out, int out_size, void* d_ws, size_t ws_size,
                              hipStream_t stream) {
  const float* X  = (const float*)d_in[0];
  const float* F  = (const float*)d_in[1];
  const int*   N  = (const int*)d_in[2];
  const float* H  = (const float*)d_in[3];
  const float* G  = (const float*)d_in[4];
  const float* Gb = (const float*)d_in[5];
  float* Y = (float*)d_out;
  __hip_bfloat16* Q = (__hip_bfloat16*)d_ws;   // KR*64*2 = 8 MiB scratch

  q_kernel<<<1024, 256, 0, stream>>>(X, F, H, Q);
  gather_gemm_kernel<<<1024, 256, 0, stream>>>((const unsigned short*)Q, N, G, Gb, Y);
}

// Round 3
// 103.889 us; speedup vs baseline: 1.4445x; 1.4445x over previous
//
#include <hip/hip_runtime.h>
#include <hip/hip_fp16.h>
#include <math.h>

// K=4, R=16384, kappa=32, NX=3, NF=13, DOUT=64, n=16
#define KR 65536
#define KAPPA 32

typedef __attribute__((ext_vector_type(8))) _Float16 f16x8;  // MFMA A/B frag
typedef __attribute__((ext_vector_type(4))) float f32x4;     // MFMA C/D frag

// packed fp16 max (v_pk_max_f16), carrier = u32
static __device__ __forceinline__ unsigned pkmax(unsigned a, unsigned b) {
  unsigned r;
  asm("v_pk_max_f16 %0, %1, %2" : "=v"(r) : "v"(a), "v"(b));
  return r;
}

// ---------------------------------------------------------------------------
// Kernel 1: Q[point][d] = dot(P[point], H[d]), P=[X|F] (16), stored fp16.
// 1024 blocks x 256 threads, 64 points/block. X/F staged to LDS coalesced;
// compute reads are wave-uniform ds_read_b128 broadcasts.
// ---------------------------------------------------------------------------
__global__ __launch_bounds__(256) void q_kernel(
    const float* __restrict__ X, const float* __restrict__ F,
    const float* __restrict__ H, _Float16* __restrict__ Q) {
  __shared__ float Pl[64 * 16];
  const int t = threadIdx.x;
  const int base = blockIdx.x * 64;

  if (t < 192) Pl[(t / 3) * 16 + (t % 3)] = X[(size_t)base * 3 + t];
  for (int j = t; j < 832; j += 256)
    Pl[(j / 13) * 16 + 3 + (j % 13)] = F[(size_t)base * 13 + j];

  const int lane = t & 63, wave = t >> 6;
  const float4 h0 = *(const float4*)(H + lane * 16 + 0);
  const float4 h1 = *(const float4*)(H + lane * 16 + 4);
  const float4 h2 = *(const float4*)(H + lane * 16 + 8);
  const float4 h3 = *(const float4*)(H + lane * 16 + 12);
  __syncthreads();

  #pragma unroll 4
  for (int p = 0; p < 16; ++p) {
    const int lp = wave * 16 + p;
    const float4* pp = (const float4*)(Pl + lp * 16);  // broadcast b128 reads
    const float4 p0 = pp[0], p1 = pp[1], p2 = pp[2], p3 = pp[3];
    float q = p0.x * h0.x + p0.y * h0.y + p0.z * h0.z + p0.w * h0.w
            + p1.x * h1.x + p1.y * h1.y + p1.z * h1.z + p1.w * h1.w
            + p2.x * h2.x + p2.y * h2.y + p2.z * h2.z + p2.w * h2.w
            + p3.x * h3.x + p3.y * h3.y + p3.z * h3.z + p3.w * h3.w;
    Q[(size_t)(base + lp) * 64 + lane] = (_Float16)q;
  }
}

// ---------------------------------------------------------------------------
// Kernel 2: m[d] = max(0, max_i Q[k,N[k,r,i],d]);  Y = relu(m @ gamma + b)
// 1024 blocks x 256 threads, 64 points/block, XCD swizzle for L2 residency.
// Phase A: 8-lane groups load full 128B Q-rows as dwordx4 (4 loads/point),
//          4 independent v_pk_max_f16 accumulator chains, indices via shfl.
// Phase B: mfma_f32_16x16x32_f16, 8 MFMA/wave; gamma transposed fp16 in LDS.
// ---------------------------------------------------------------------------
__global__ __launch_bounds__(256) void gather_gemm_kernel(
    const _Float16* __restrict__ Q, const int* __restrict__ N,
    const float* __restrict__ gamma, const float* __restrict__ gbias,
    float* __restrict__ Y) {
  __shared__ _Float16 Gt[64 * 72];  // Gt[e][d], stride 72 halves (16B-aligned rows)
  __shared__ _Float16 Ml[64 * 72];  // Ml[p][d]
  __shared__ float Bl[64];

  const int t = threadIdx.x;
  // stage gamma transposed -> fp16 (one-time)
  for (int i = t; i < 1024; i += 256) {
    const float4 gv = ((const float4*)gamma)[i];
    const int d = i >> 4, e0 = (i & 15) * 4;
    Gt[(e0 + 0) * 72 + d] = (_Float16)gv.x;
    Gt[(e0 + 1) * 72 + d] = (_Float16)gv.y;
    Gt[(e0 + 2) * 72 + d] = (_Float16)gv.z;
    Gt[(e0 + 3) * 72 + d] = (_Float16)gv.w;
  }
  if (t < 64) Bl[t] = gbias[t];

  // XCD-aware bijective remap (1024 = 8 xcd x 128): XCD pair {2k,2k+1} <- slice k
  const int b = blockIdx.x;
  const int xcd = b & 7, bi = b >> 3;
  const int k = xcd >> 1, halfsel = xcd & 1;
  const int base = (k * 256 + halfsel * 128 + bi) * 64;

  const int lane = t & 63, wave = t >> 6;
  const int grp = lane >> 3, member = lane & 7;  // 8 groups x 8 lanes
  const _Float16* Qk = Q + ((size_t)k << 20);    // k * R * 64

  // ---- Phase A: two octets of 8 points per wave ----
  #pragma unroll
  for (int oct = 0; oct < 2; ++oct) {
    const int p0 = base + wave * 16 + oct * 8;
    // lane l holds N[p0*32 + 4l .. 4l+3]
    const int4 c = ((const int4*)(N + (size_t)p0 * 32))[lane];
    unsigned m0 = 0u, m1 = 0u, m2 = 0u, m3 = 0u;  // relu folded: start at +0
    #pragma unroll
    for (int jq = 0; jq < 8; ++jq) {
      const int src = (lane & 0x38) + jq;  // holder of my group's neighbors 4jq..4jq+3
      const int i0 = __shfl(c.x, src);
      const int i1 = __shfl(c.y, src);
      const int i2 = __shfl(c.z, src);
      const int i3 = __shfl(c.w, src);
      int4 v;
      v = *(const int4*)(Qk + (size_t)i0 * 64 + member * 8);
      m0 = pkmax(m0, v.x); m1 = pkmax(m1, v.y); m2 = pkmax(m2, v.z); m3 = pkmax(m3, v.w);
      v = *(const int4*)(Qk + (size_t)i1 * 64 + member * 8);
      m0 = pkmax(m0, v.x); m1 = pkmax(m1, v.y); m2 = pkmax(m2, v.z); m3 = pkmax(m3, v.w);
      v = *(const int4*)(Qk + (size_t)i2 * 64 + member * 8);
      m0 = pkmax(m0, v.x); m1 = pkmax(m1, v.y); m2 = pkmax(m2, v.z); m3 = pkmax(m3, v.w);
      v = *(const int4*)(Qk + (size_t)i3 * 64 + member * 8);
      m0 = pkmax(m0, v.x); m1 = pkmax(m1, v.y); m2 = pkmax(m2, v.z); m3 = pkmax(m3, v.w);
    }
    // group grp owns point p0+grp; member owns channels 8*member..+7
    int4 mv; mv.x = (int)m0; mv.y = (int)m1; mv.z = (int)m2; mv.w = (int)m3;
    *(int4*)(Ml + (wave * 16 + oct * 8 + grp) * 72 + member * 8) = mv;  // b128
  }
  __syncthreads();

  // ---- Phase B: C(64x64) = Ml @ Gt^T via mfma 16x16x32 f16 ----
  const int ln15 = lane & 15, quad = lane >> 4;
  f32x4 acc[4] = {{0.f,0.f,0.f,0.f},{0.f,0.f,0.f,0.f},{0.f,0.f,0.f,0.f},{0.f,0.f,0.f,0.f}};
  #pragma unroll
  for (int ks = 0; ks < 2; ++ks) {
    // A[m][k]: m = lane&15 (tile row), k = quad*8+j (+32*ks)
    const f16x8 af = *(const f16x8*)(Ml + (wave * 16 + ln15) * 72 + ks * 32 + quad * 8);
    #pragma unroll
    for (int nt = 0; nt < 4; ++nt) {
      // B[k][n]: n = lane&15, k = quad*8+j (+32*ks); Gt[e][d] = gamma[d][e]
      const f16x8 bf = *(const f16x8*)(Gt + (nt * 16 + ln15) * 72 + ks * 32 + quad * 8);
      acc[nt] = __builtin_amdgcn_mfma_f32_16x16x32_f16(af, bf, acc[nt], 0, 0, 0);
    }
  }

  // epilogue: C/D layout col=lane&15, row=quad*4+reg
  #pragma unroll
  for (int nt = 0; nt < 4; ++nt) {
    const float bv = Bl[nt * 16 + ln15];
    #pragma unroll
    for (int r = 0; r < 4; ++r) {
      const float y = fmaxf(acc[nt][r] + bv, 0.0f);
      Y[(size_t)(base + wave * 16 + quad * 4 + r) * 64 + nt * 16 + ln15] = y;
    }
  }
}

extern "C" void kernel_launch(void* const* d_in, const int* in_sizes, int n_in,
                              void* d_out, int out_size, void* d_ws, size_t ws_size,
                              hipStream_t stream) {
  const float* X  = (const float*)d_in[0];
  const float* F  = (const float*)d_in[1];
  const int*   N  = (const int*)d_in[2];
  const float* H  = (const float*)d_in[3];
  const float* G  = (const float*)d_in[4];
  const float* Gb = (const float*)d_in[5];
  float* Y = (float*)d_out;
  _Float16* Q = (_Float16*)d_ws;  // KR*64*2 = 8 MiB scratch

  q_kernel<<<1024, 256, 0, stream>>>(X, F, H, Q);
  gather_gemm_kernel<<<1024, 256, 0, stream>>>(Q, N, G, Gb, Y);
}

// Round 4
// 99.650 us; speedup vs baseline: 1.5059x; 1.0425x over previous
//
#include <hip/hip_runtime.h>
#include <hip/hip_fp16.h>
#include <math.h>

// K=4, R=16384, kappa=32, NX=3, NF=13, DOUT=64, n=16
#define KR 65536
#define KAPPA 32

typedef __attribute__((ext_vector_type(8))) _Float16 f16x8;  // MFMA A/B frag
typedef __attribute__((ext_vector_type(4))) float f32x4;     // MFMA C/D frag

// packed fp16 max (v_pk_max_f16), carrier = u32
static __device__ __forceinline__ unsigned pkmax(unsigned a, unsigned b) {
  unsigned r;
  asm("v_pk_max_f16 %0, %1, %2" : "=v"(r) : "v"(a), "v"(b));
  return r;
}

// ---------------------------------------------------------------------------
// Kernel 1: Q[point][d] = dot(P[point], H[d]), P=[X|F] (16), stored fp16.
// 1024 blocks x 256 threads, 64 points/block. X/F staged to LDS coalesced;
// compute reads are wave-uniform ds_read_b128 broadcasts.
// ---------------------------------------------------------------------------
__global__ __launch_bounds__(256) void q_kernel(
    const float* __restrict__ X, const float* __restrict__ F,
    const float* __restrict__ H, _Float16* __restrict__ Q) {
  __shared__ float Pl[64 * 16];
  const int t = threadIdx.x;
  const int base = blockIdx.x * 64;

  if (t < 192) Pl[(t / 3) * 16 + (t % 3)] = X[(size_t)base * 3 + t];
  for (int j = t; j < 832; j += 256)
    Pl[(j / 13) * 16 + 3 + (j % 13)] = F[(size_t)base * 13 + j];

  const int lane = t & 63, wave = t >> 6;
  const float4 h0 = *(const float4*)(H + lane * 16 + 0);
  const float4 h1 = *(const float4*)(H + lane * 16 + 4);
  const float4 h2 = *(const float4*)(H + lane * 16 + 8);
  const float4 h3 = *(const float4*)(H + lane * 16 + 12);
  __syncthreads();

  #pragma unroll 4
  for (int p = 0; p < 16; ++p) {
    const int lp = wave * 16 + p;
    const float4* pp = (const float4*)(Pl + lp * 16);  // broadcast b128 reads
    const float4 p0 = pp[0], p1 = pp[1], p2 = pp[2], p3 = pp[3];
    float q = p0.x * h0.x + p0.y * h0.y + p0.z * h0.z + p0.w * h0.w
            + p1.x * h1.x + p1.y * h1.y + p1.z * h1.z + p1.w * h1.w
            + p2.x * h2.x + p2.y * h2.y + p2.z * h2.z + p2.w * h2.w
            + p3.x * h3.x + p3.y * h3.y + p3.z * h3.z + p3.w * h3.w;
    Q[(size_t)(base + lp) * 64 + lane] = (_Float16)q;
  }
}

// ---------------------------------------------------------------------------
// Kernel 2: m[d] = max(0, max_i Q[k,N[k,r,i],d]);  Y = relu(m @ gamma + b)
// 2048 blocks x 256 threads, 32 points/block (8 blocks/CU = 32 waves/CU).
// XCD swizzle: 2048 = 8 xcd x 256; XCD pair {2k,2k+1} serves k-slice k so
// each XCD's gather set is one fp16 Q-slice (2 MiB) -> L2-resident.
// Phase A: 8-lane groups, 1 point/group/wave-octet; neighbor indices via
//          group-broadcast int4 global loads (no shfl); Q rows as dwordx4;
//          4 independent v_pk_max_f16 chains.
// Phase B: mfma_f32_16x16x32_f16; each wave one 16x32 tile of C(32x64).
// ---------------------------------------------------------------------------
__global__ __launch_bounds__(256) void gather_gemm_kernel(
    const _Float16* __restrict__ Q, const int* __restrict__ N,
    const float* __restrict__ gamma, const float* __restrict__ gbias,
    float* __restrict__ Y) {
  __shared__ _Float16 Gt[64 * 72];  // Gt[e][d] (transposed gamma), 9.2 KB
  __shared__ _Float16 Ml[32 * 72];  // Ml[p][d], 4.6 KB
  __shared__ float Bl[64];

  const int t = threadIdx.x;
  // stage gamma transposed -> fp16
  #pragma unroll
  for (int ii = 0; ii < 4; ++ii) {
    const int i = t + ii * 256;
    const float4 gv = ((const float4*)gamma)[i];
    const int d = i >> 4, e0 = (i & 15) * 4;
    Gt[(e0 + 0) * 72 + d] = (_Float16)gv.x;
    Gt[(e0 + 1) * 72 + d] = (_Float16)gv.y;
    Gt[(e0 + 2) * 72 + d] = (_Float16)gv.z;
    Gt[(e0 + 3) * 72 + d] = (_Float16)gv.w;
  }
  if (t < 64) Bl[t] = gbias[t];

  // XCD-aware bijective remap: 2048 = 8 xcd x 256 blocks
  const int b = blockIdx.x;
  const int xcd = b & 7, bi = b >> 3;          // bi in [0,256)
  const int k = xcd >> 1, halfsel = xcd & 1;   // k-slice, half
  const int base = k * 16384 + (halfsel * 256 + bi) * 32;  // first point

  const int lane = t & 63, wave = t >> 6;
  const int grp = lane >> 3, member = lane & 7;  // 8 groups x 8 lanes
  const _Float16* Qk = Q + ((size_t)k << 20);    // k * R * 64

  // ---- Phase A: one octet (8 points) per wave ----
  const int p0 = base + wave * 8;          // wave's first point
  const int mypt = p0 + grp;               // this group's point
  const int* nbase = N + (size_t)mypt * KAPPA;
  unsigned m0 = 0u, m1 = 0u, m2 = 0u, m3 = 0u;  // relu folded: start at +0
  #pragma unroll
  for (int jq = 0; jq < 8; ++jq) {
    // group-broadcast 16B index load (same addr across the 8 lanes of a group)
    const int4 c = *(const int4*)(nbase + jq * 4);
    int4 v;
    v = *(const int4*)(Qk + (size_t)c.x * 64 + member * 8);
    m0 = pkmax(m0, v.x); m1 = pkmax(m1, v.y); m2 = pkmax(m2, v.z); m3 = pkmax(m3, v.w);
    v = *(const int4*)(Qk + (size_t)c.y * 64 + member * 8);
    m0 = pkmax(m0, v.x); m1 = pkmax(m1, v.y); m2 = pkmax(m2, v.z); m3 = pkmax(m3, v.w);
    v = *(const int4*)(Qk + (size_t)c.z * 64 + member * 8);
    m0 = pkmax(m0, v.x); m1 = pkmax(m1, v.y); m2 = pkmax(m2, v.z); m3 = pkmax(m3, v.w);
    v = *(const int4*)(Qk + (size_t)c.w * 64 + member * 8);
    m0 = pkmax(m0, v.x); m1 = pkmax(m1, v.y); m2 = pkmax(m2, v.z); m3 = pkmax(m3, v.w);
  }
  {
    int4 mv; mv.x = (int)m0; mv.y = (int)m1; mv.z = (int)m2; mv.w = (int)m3;
    *(int4*)(Ml + (wave * 8 + grp) * 72 + member * 8) = mv;  // ds_write_b128
  }
  __syncthreads();

  // ---- Phase B: C(32x64) = Ml @ Gt^T via mfma 16x16x32 f16 ----
  // wave w: row tile (w&1) -> rows (w&1)*16..+15; col tile (w>>1) -> cols (w>>1)*32..+31
  const int ln15 = lane & 15, quad = lane >> 4;
  const int rt = wave & 1, ct = wave >> 1;
  f32x4 acc[2] = {{0.f,0.f,0.f,0.f},{0.f,0.f,0.f,0.f}};
  #pragma unroll
  for (int ks = 0; ks < 2; ++ks) {
    // A[m][k]: m = ln15 (tile row), k = quad*8+j (+32*ks)
    const f16x8 af = *(const f16x8*)(Ml + (rt * 16 + ln15) * 72 + ks * 32 + quad * 8);
    #pragma unroll
    for (int nt = 0; nt < 2; ++nt) {
      const f16x8 bf = *(const f16x8*)(Gt + (ct * 32 + nt * 16 + ln15) * 72 + ks * 32 + quad * 8);
      acc[nt] = __builtin_amdgcn_mfma_f32_16x16x32_f16(af, bf, acc[nt], 0, 0, 0);
    }
  }

  // epilogue: C/D layout col=lane&15, row=quad*4+reg
  #pragma unroll
  for (int nt = 0; nt < 2; ++nt) {
    const float bv = Bl[ct * 32 + nt * 16 + ln15];
    #pragma unroll
    for (int r = 0; r < 4; ++r) {
      const float y = fmaxf(acc[nt][r] + bv, 0.0f);
      Y[(size_t)(base + rt * 16 + quad * 4 + r) * 64 + ct * 32 + nt * 16 + ln15] = y;
    }
  }
}

extern "C" void kernel_launch(void* const* d_in, const int* in_sizes, int n_in,
                              void* d_out, int out_size, void* d_ws, size_t ws_size,
                              hipStream_t stream) {
  const float* X  = (const float*)d_in[0];
  const float* F  = (const float*)d_in[1];
  const int*   N  = (const int*)d_in[2];
  const float* H  = (const float*)d_in[3];
  const float* G  = (const float*)d_in[4];
  const float* Gb = (const float*)d_in[5];
  float* Y = (float*)d_out;
  _Float16* Q = (_Float16*)d_ws;  // KR*64*2 = 8 MiB scratch

  q_kernel<<<1024, 256, 0, stream>>>(X, F, H, Q);
  gather_gemm_kernel<<<2048, 256, 0, stream>>>(Q, N, G, Gb, Y);
}

// Round 5
// 99.622 us; speedup vs baseline: 1.5064x; 1.0003x over previous
//
#include <hip/hip_runtime.h>
#include <hip/hip_fp16.h>
#include <math.h>

// K=4, R=16384, kappa=32, NX=3, NF=13, DOUT=64, n=16
#define KR 65536
#define KAPPA 32

typedef __attribute__((ext_vector_type(8))) _Float16 f16x8;  // MFMA A/B frag, 16B
typedef __attribute__((ext_vector_type(4))) float f32x4;     // MFMA C/D frag

// ---------------------------------------------------------------------------
// Kernel 1: Q[point][d] = dot(P[point], H[d]), P=[X|F] (16), stored fp16.
// 1024 blocks x 256 threads, 64 points/block. X/F staged to LDS coalesced;
// compute reads are wave-uniform ds_read_b128 broadcasts.
// ---------------------------------------------------------------------------
__global__ __launch_bounds__(256) void q_kernel(
    const float* __restrict__ X, const float* __restrict__ F,
    const float* __restrict__ H, _Float16* __restrict__ Q) {
  __shared__ float Pl[64 * 16];
  const int t = threadIdx.x;
  const int base = blockIdx.x * 64;

  if (t < 192) Pl[(t / 3) * 16 + (t % 3)] = X[(size_t)base * 3 + t];
  for (int j = t; j < 832; j += 256)
    Pl[(j / 13) * 16 + 3 + (j % 13)] = F[(size_t)base * 13 + j];

  const int lane = t & 63, wave = t >> 6;
  const float4 h0 = *(const float4*)(H + lane * 16 + 0);
  const float4 h1 = *(const float4*)(H + lane * 16 + 4);
  const float4 h2 = *(const float4*)(H + lane * 16 + 8);
  const float4 h3 = *(const float4*)(H + lane * 16 + 12);
  __syncthreads();

  #pragma unroll 4
  for (int p = 0; p < 16; ++p) {
    const int lp = wave * 16 + p;
    const float4* pp = (const float4*)(Pl + lp * 16);  // broadcast b128 reads
    const float4 p0 = pp[0], p1 = pp[1], p2 = pp[2], p3 = pp[3];
    float q = p0.x * h0.x + p0.y * h0.y + p0.z * h0.z + p0.w * h0.w
            + p1.x * h1.x + p1.y * h1.y + p1.z * h1.z + p1.w * h1.w
            + p2.x * h2.x + p2.y * h2.y + p2.z * h2.z + p2.w * h2.w
            + p3.x * h3.x + p3.y * h3.y + p3.z * h3.z + p3.w * h3.w;
    Q[(size_t)(base + lp) * 64 + lane] = (_Float16)q;
  }
}

// ---------------------------------------------------------------------------
// Kernel 2: m[d] = max(0, max_i Q[k,N[k,r,i],d]);  Y = relu(m @ gamma + b)
// 2048 blocks x 256 threads, 32 points/block.
// XCD swizzle: 2048 = 8 xcd x 256; XCD pair {2k,2k+1} serves k-slice k so
// each XCD's gather set is one fp16 Q-slice (2 MiB) -> L2-resident.
// Phase A: 8-lane groups, 1 point/group; ALL 8 index int4 loads hoisted
//          (independent issue), then 32 row loads (dwordx4) drain into
//          v_pk_max_f16 trees (builtin max -> scheduler-visible).
// Phase B: mfma_f32_16x16x32_f16; each wave one 16x32 tile of C(32x64).
// ---------------------------------------------------------------------------
__global__ __launch_bounds__(256) void gather_gemm_kernel(
    const _Float16* __restrict__ Q, const int* __restrict__ N,
    const float* __restrict__ gamma, const float* __restrict__ gbias,
    float* __restrict__ Y) {
  __shared__ _Float16 Gt[64 * 72];  // Gt[e][d] (transposed gamma), 9.2 KB
  __shared__ _Float16 Ml[32 * 72];  // Ml[p][d], 4.6 KB
  __shared__ float Bl[64];

  const int t = threadIdx.x;
  // stage gamma transposed -> fp16
  #pragma unroll
  for (int ii = 0; ii < 4; ++ii) {
    const int i = t + ii * 256;
    const float4 gv = ((const float4*)gamma)[i];
    const int d = i >> 4, e0 = (i & 15) * 4;
    Gt[(e0 + 0) * 72 + d] = (_Float16)gv.x;
    Gt[(e0 + 1) * 72 + d] = (_Float16)gv.y;
    Gt[(e0 + 2) * 72 + d] = (_Float16)gv.z;
    Gt[(e0 + 3) * 72 + d] = (_Float16)gv.w;
  }
  if (t < 64) Bl[t] = gbias[t];

  // XCD-aware bijective remap: 2048 = 8 xcd x 256 blocks
  const int b = blockIdx.x;
  const int xcd = b & 7, bi = b >> 3;          // bi in [0,256)
  const int k = xcd >> 1, halfsel = xcd & 1;   // k-slice, half
  const int base = k * 16384 + (halfsel * 256 + bi) * 32;  // first point

  const int lane = t & 63, wave = t >> 6;
  const int grp = lane >> 3, member = lane & 7;  // 8 groups x 8 lanes
  const _Float16* Qk = Q + ((size_t)k << 20);    // k * R * 64

  // ---- Phase A: one point per 8-lane group ----
  const int mypt = base + wave * 8 + grp;
  const int4* nbase = (const int4*)(N + (size_t)mypt * KAPPA);

  // hoist all 8 index loads: independent, 8 outstanding before any row load
  int4 c0 = nbase[0], c1 = nbase[1], c2 = nbase[2], c3 = nbase[3];
  int4 c4 = nbase[4], c5 = nbase[5], c6 = nbase[6], c7 = nbase[7];

  f16x8 m = {0, 0, 0, 0, 0, 0, 0, 0};  // relu folded: start at +0
  const _Float16* qb = Qk + member * 8;
  #define GSTEP(c)                                                            \
    {                                                                         \
      const f16x8 v0 = *(const f16x8*)(qb + (size_t)(c).x * 64);              \
      const f16x8 v1 = *(const f16x8*)(qb + (size_t)(c).y * 64);              \
      const f16x8 v2 = *(const f16x8*)(qb + (size_t)(c).z * 64);              \
      const f16x8 v3 = *(const f16x8*)(qb + (size_t)(c).w * 64);              \
      const f16x8 t01 = __builtin_elementwise_max(v0, v1);                    \
      const f16x8 t23 = __builtin_elementwise_max(v2, v3);                    \
      m = __builtin_elementwise_max(m, __builtin_elementwise_max(t01, t23));  \
    }
  GSTEP(c0) GSTEP(c1) GSTEP(c2) GSTEP(c3)
  GSTEP(c4) GSTEP(c5) GSTEP(c6) GSTEP(c7)
  #undef GSTEP

  *(f16x8*)(Ml + (wave * 8 + grp) * 72 + member * 8) = m;  // ds_write_b128
  __syncthreads();

  // ---- Phase B: C(32x64) = Ml @ Gt^T via mfma 16x16x32 f16 ----
  // wave w: rows (w&1)*16..+15; cols (w>>1)*32..+31
  const int ln15 = lane & 15, quad = lane >> 4;
  const int rt = wave & 1, ct = wave >> 1;
  f32x4 acc[2] = {{0.f, 0.f, 0.f, 0.f}, {0.f, 0.f, 0.f, 0.f}};
  #pragma unroll
  for (int ks = 0; ks < 2; ++ks) {
    const f16x8 af = *(const f16x8*)(Ml + (rt * 16 + ln15) * 72 + ks * 32 + quad * 8);
    #pragma unroll
    for (int nt = 0; nt < 2; ++nt) {
      const f16x8 bf = *(const f16x8*)(Gt + (ct * 32 + nt * 16 + ln15) * 72 + ks * 32 + quad * 8);
      acc[nt] = __builtin_amdgcn_mfma_f32_16x16x32_f16(af, bf, acc[nt], 0, 0, 0);
    }
  }

  // epilogue: C/D layout col=lane&15, row=quad*4+reg
  #pragma unroll
  for (int nt = 0; nt < 2; ++nt) {
    const float bv = Bl[ct * 32 + nt * 16 + ln15];
    #pragma unroll
    for (int r = 0; r < 4; ++r) {
      const float y = fmaxf(acc[nt][r] + bv, 0.0f);
      Y[(size_t)(base + rt * 16 + quad * 4 + r) * 64 + ct * 32 + nt * 16 + ln15] = y;
    }
  }
}

extern "C" void kernel_launch(void* const* d_in, const int* in_sizes, int n_in,
                              void* d_out, int out_size, void* d_ws, size_t ws_size,
                              hipStream_t stream) {
  const float* X  = (const float*)d_in[0];
  const float* F  = (const float*)d_in[1];
  const int*   N  = (const int*)d_in[2];
  const float* H  = (const float*)d_in[3];
  const float* G  = (const float*)d_in[4];
  const float* Gb = (const float*)d_in[5];
  float* Y = (float*)d_out;
  _Float16* Q = (_Float16*)d_ws;  // KR*64*2 = 8 MiB scratch

  q_kernel<<<1024, 256, 0, stream>>>(X, F, H, Q);
  gather_gemm_kernel<<<2048, 256, 0, stream>>>(Q, N, G, Gb, Y);
}